// Round 4
// baseline (771.333 us; speedup 1.0000x reference)
//
#include <hip/hip_runtime.h>

#define T_TOK 4096
#define DM 1024
#define DF 4096
#define NE 8
#define BM 128
#define RCAP 9216   // 8192 + 8*128 worst-case padding
#define MAXT 72     // RCAP / BM
#define CHUNK_B 8192    // 64x64 fp16 swizzled chunk
#define ACH_B 16384     // 128x64 fp16 swizzled chunk

typedef _Float16 f16x8 __attribute__((ext_vector_type(8)));
typedef float f32x4 __attribute__((ext_vector_type(4)));

#define MFMA16(a, b, c) __builtin_amdgcn_mfma_f32_16x16x32_f16(a, b, c, 0, 0, 0)

__device__ __forceinline__ ushort f2h_bits(float f) {
    _Float16 h = (_Float16)f;
    return __builtin_bit_cast(unsigned short, h);
}

__device__ __forceinline__ uint4 pack8(float4 a, float4 b) {
    union { ushort u[8]; uint4 v; } r;
    r.u[0] = f2h_bits(a.x); r.u[1] = f2h_bits(a.y);
    r.u[2] = f2h_bits(a.z); r.u[3] = f2h_bits(a.w);
    r.u[4] = f2h_bits(b.x); r.u[5] = f2h_bits(b.y);
    r.u[6] = f2h_bits(b.z); r.u[7] = f2h_bits(b.w);
    return r.v;
}

// async global->LDS, 16B per lane; lds ptr must be wave-uniform
__device__ __forceinline__ void gll16(const void* g, void* l) {
    __builtin_amdgcn_global_load_lds(
        (const __attribute__((address_space(1))) unsigned int*)g,
        (__attribute__((address_space(3))) unsigned int*)l, 16, 0, 0);
}

// ---------------- init ----------------
__global__ __launch_bounds__(256) void k_init(float* __restrict__ out,
                                              int* __restrict__ misc,
                                              int* __restrict__ row_tok) {
    int i = blockIdx.x * 256 + threadIdx.x;
    if (i < T_TOK * DM + 1) out[i] = 0.f;
    if (i < RCAP) row_tok[i] = -1;
    if (i < 256) misc[i] = 0;   // cnt[8], fill[8], poff[8], texp[72]
}

// ---------------- router ----------------
__global__ __launch_bounds__(64) void k_router(const float* __restrict__ x,
                                               const float* __restrict__ Wr,
                                               float* __restrict__ probs,
                                               int* __restrict__ topi,
                                               float* __restrict__ topw,
                                               int* __restrict__ cnt) {
    int t = blockIdx.x;
    int lane = threadIdx.x;
    const float* xr = x + (size_t)t * DM;
    float s[NE];
#pragma unroll
    for (int e = 0; e < NE; e++) s[e] = 0.f;
    for (int j = lane; j < DM; j += 64) {
        float xv = xr[j];
#pragma unroll
        for (int e = 0; e < NE; e++) s[e] += xv * Wr[e * DM + j];
    }
#pragma unroll
    for (int off = 32; off > 0; off >>= 1) {
#pragma unroll
        for (int e = 0; e < NE; e++) s[e] += __shfl_xor(s[e], off, 64);
    }
    if (lane == 0) {
        float mx = s[0];
#pragma unroll
        for (int e = 1; e < NE; e++) mx = fmaxf(mx, s[e]);
        float ex[NE], sum = 0.f;
#pragma unroll
        for (int e = 0; e < NE; e++) { ex[e] = expf(s[e] - mx); sum += ex[e]; }
        float inv = 1.f / sum;
        float p[NE];
#pragma unroll
        for (int e = 0; e < NE; e++) { p[e] = ex[e] * inv; probs[t * NE + e] = p[e]; }
        int i0 = 0;
#pragma unroll
        for (int e = 1; e < NE; e++) if (p[e] > p[i0]) i0 = e;
        int i1 = (i0 == 0) ? 1 : 0;
#pragma unroll
        for (int e = 0; e < NE; e++) if (e != i0 && p[e] > p[i1]) i1 = e;
        float w0 = p[i0], w1 = p[i1], winv = 1.f / (w0 + w1);
        topi[2 * t] = i0;     topw[2 * t] = w0 * winv;
        topi[2 * t + 1] = i1; topw[2 * t + 1] = w1 * winv;
        atomicAdd(&cnt[i0], 1);
        atomicAdd(&cnt[i1], 1);
    }
}

// ---------------- scan ----------------
__global__ __launch_bounds__(256) void k_scan(const float* __restrict__ probs,
                                              const int* __restrict__ cnt,
                                              int* __restrict__ poff,
                                              int* __restrict__ texp,
                                              float* __restrict__ aux_out) {
    __shared__ float red[256 * NE];
    int tid = threadIdx.x;
    float part[NE];
#pragma unroll
    for (int e = 0; e < NE; e++) part[e] = 0.f;
    for (int t = tid; t < T_TOK; t += 256) {
#pragma unroll
        for (int e = 0; e < NE; e++) part[e] += probs[t * NE + e];
    }
#pragma unroll
    for (int e = 0; e < NE; e++) red[tid * NE + e] = part[e];
    __syncthreads();
    for (int s2 = 128; s2 > 0; s2 >>= 1) {
        if (tid < s2) {
#pragma unroll
            for (int e = 0; e < NE; e++) red[tid * NE + e] += red[(tid + s2) * NE + e];
        }
        __syncthreads();
    }
    if (tid == 0) {
        float al = 0.f;
#pragma unroll
        for (int e = 0; e < NE; e++) al += red[e] * (float)cnt[e];
        *aux_out = al * (8.0f / (16777216.0f + 1e-6f));
        int run = 0, tix = 0;
        for (int e = 0; e < NE; e++) {
            poff[e] = run;
            int nt = (cnt[e] + BM - 1) / BM;
            for (int i = 0; i < nt; i++) texp[tix++] = e;
            run += nt * BM;
        }
    }
}

// ---------------- assign ----------------
__global__ __launch_bounds__(256) void k_assign(const int* __restrict__ topi,
                                                const float* __restrict__ topw,
                                                const int* __restrict__ poff,
                                                int* __restrict__ fill,
                                                int* __restrict__ row_tok,
                                                float* __restrict__ row_w) {
    int t = blockIdx.x * 256 + threadIdx.x;
    if (t >= T_TOK) return;
#pragma unroll
    for (int k = 0; k < 2; k++) {
        int e = topi[2 * t + k];
        int pos = atomicAdd(&fill[e], 1);
        int r = poff[e] + pos;
        row_tok[r] = t;
        row_w[r] = topw[2 * t + k];
    }
}

// convert fp32 row-major [rows][row_len] -> tile-ordered swizzled fp16 chunks
// chunk (rt, kt) = 64x64, element (r,c) at byte r*128 + ((2c) ^ ((r&7)<<4))
__global__ __launch_bounds__(256) void k_convert(const float* __restrict__ src,
                                                 ushort* __restrict__ dst,
                                                 int row_len) {
    int nk = row_len >> 6;
    int kt = blockIdx.x, rt = blockIdx.y;
    int tid = threadIdx.x;
    int r = tid >> 2, c0 = (tid & 3) * 16;
    const float* s = src + (size_t)(rt * 64 + r) * row_len + kt * 64 + c0;
    float4 v0 = *(const float4*)(s);
    float4 v1 = *(const float4*)(s + 4);
    float4 v2 = *(const float4*)(s + 8);
    float4 v3 = *(const float4*)(s + 12);
    char* chunk = (char*)dst + ((size_t)rt * nk + kt) * CHUNK_B;
    int sw = (r & 7) << 4;
    *(uint4*)(chunk + r * 128 + ((2 * c0) ^ sw)) = pack8(v0, v1);
    *(uint4*)(chunk + r * 128 + ((2 * c0 + 16) ^ sw)) = pack8(v2, v3);
}

// gather x rows into tile-ordered swizzled fp16: chunk (rt, kt) = 128x64
__global__ __launch_bounds__(256) void k_gather_t(const float* __restrict__ x,
                                                  const int* __restrict__ row_tok,
                                                  ushort* __restrict__ xg) {
    int kt = blockIdx.x, rt = blockIdx.y;
    int tid = threadIdx.x;
    int r = tid >> 1, c0 = (tid & 1) * 32;
    int tok = row_tok[rt * BM + r];
    char* chunk = (char*)xg + ((size_t)rt * 16 + kt) * ACH_B;
    int sw = (r & 7) << 4;
    if (tok >= 0) {
        const float* s = x + (size_t)tok * DM + kt * 64 + c0;
#pragma unroll
        for (int j = 0; j < 4; j++) {
            float4 va = *(const float4*)(s + j * 8);
            float4 vb = *(const float4*)(s + j * 8 + 4);
            *(uint4*)(chunk + r * 128 + ((2 * (c0 + j * 8)) ^ sw)) = pack8(va, vb);
        }
    } else {
        uint4 z = {0, 0, 0, 0};
#pragma unroll
        for (int j = 0; j < 4; j++)
            *(uint4*)(chunk + r * 128 + ((2 * (c0 + j * 8)) ^ sw)) = z;
    }
}

// GEMM1: 128x128 fused dual-B tile, 8 waves, 2-buffer counted-vmcnt pipeline
__global__ __launch_bounds__(512, 2) void k_gemm1_t(const ushort* __restrict__ xg,
                                                    const ushort* __restrict__ W1h,
                                                    const ushort* __restrict__ W3h,
                                                    const int* __restrict__ texp,
                                                    ushort* __restrict__ hbuf) {
    __shared__ __align__(16) char lA[2][16384];
    __shared__ __align__(16) char lB1[2][16384];
    __shared__ __align__(16) char lB3[2][16384];
    int ct = blockIdx.x, rt = blockIdx.y;   // ct in [0,32): 128 cols of DF
    int e = texp[rt];
    const char* Ac  = (const char*)xg + (size_t)rt * 16 * ACH_B;
    const char* B1c = (const char*)W1h + (size_t)((e * 64 + ct * 2) * 16) * CHUNK_B;
    const char* B3c = (const char*)W3h + (size_t)((e * 64 + ct * 2) * 16) * CHUNK_B;
    int tid = threadIdx.x, lane = tid & 63, wv = tid >> 6;
    int wr = wv >> 2, wc = wv & 3;          // wave tile: 64 rows x 32 cols
    int bch = wv >> 2;                       // which 64-col chunk of B this wave stages
    int bin = (wv & 3) * 2048;               // offset within that chunk

    const f32x4 fz = {0.f, 0.f, 0.f, 0.f};
    f32x4 acc1[4][2], acc3[4][2];
#pragma unroll
    for (int m = 0; m < 4; m++)
#pragma unroll
        for (int n = 0; n < 2; n++) { acc1[m][n] = fz; acc3[m][n] = fz; }

    // per wave per stage: 2 (A) + 2 (B1) + 2 (B3) = 6 gll16
#define G1_STAGE(kt_, b_)                                                              \
    {                                                                                  \
        const char* As_ = Ac + (kt_) * ACH_B;                                          \
        _Pragma("unroll")                                                              \
        for (int i = 0; i < 2; i++)                                                    \
            gll16(As_ + wv * 2048 + i * 1024 + lane * 16, lA[b_] + wv * 2048 + i * 1024); \
        const char* B1s_ = B1c + (size_t)(bch * 16 + (kt_)) * CHUNK_B + bin;           \
        _Pragma("unroll")                                                              \
        for (int i = 0; i < 2; i++)                                                    \
            gll16(B1s_ + i * 1024 + lane * 16, lB1[b_] + wv * 2048 + i * 1024);        \
        const char* B3s_ = B3c + (size_t)(bch * 16 + (kt_)) * CHUNK_B + bin;           \
        _Pragma("unroll")                                                              \
        for (int i = 0; i < 2; i++)                                                    \
            gll16(B3s_ + i * 1024 + lane * 16, lB3[b_] + wv * 2048 + i * 1024);        \
    }

    G1_STAGE(0, 0);
    int cur = 0;
    for (int kt = 0; kt < 16; kt++) {
        if (kt < 15) {
            G1_STAGE(kt + 1, cur ^ 1);
            asm volatile("s_waitcnt vmcnt(6)" ::: "memory");  // tile kt done, kt+1 in flight
        } else {
            asm volatile("s_waitcnt vmcnt(0)" ::: "memory");
        }
        __syncthreads();
        __builtin_amdgcn_s_setprio(1);
#pragma unroll
        for (int ks = 0; ks < 2; ks++) {
            int kbyte = (ks * 32 + (lane >> 4) * 8) * 2;
            f16x8 af[4];
#pragma unroll
            for (int m = 0; m < 4; m++) {
                int r = wr * 64 + m * 16 + (lane & 15);
                af[m] = *(const f16x8*)(lA[cur] + r * 128 + (kbyte ^ ((r & 7) << 4)));
            }
#pragma unroll
            for (int n = 0; n < 2; n++) {
                int c = wc * 32 + n * 16 + (lane & 15);
                int off = c * 128 + (kbyte ^ ((c & 7) << 4));
                f16x8 b1 = *(const f16x8*)(lB1[cur] + off);
                f16x8 b3 = *(const f16x8*)(lB3[cur] + off);
#pragma unroll
                for (int m = 0; m < 4; m++) {
                    acc1[m][n] = MFMA16(af[m], b1, acc1[m][n]);
                    acc3[m][n] = MFMA16(af[m], b3, acc3[m][n]);
                }
            }
        }
        __builtin_amdgcn_s_setprio(0);
        __syncthreads();
        cur ^= 1;
    }
#undef G1_STAGE
    // epilogue: silu(a1)*a3 -> hbuf chunks (rt, ct*2 + fl/64), swizzled
#pragma unroll
    for (int m = 0; m < 4; m++) {
#pragma unroll
        for (int i = 0; i < 4; i++) {
            int rl = wr * 64 + m * 16 + (lane >> 4) * 4 + i;   // 0..127
            int sw = (rl & 7) << 4;
#pragma unroll
            for (int n = 0; n < 2; n++) {
                int fl = wc * 32 + n * 16 + (lane & 15);        // 0..127
                float a1 = acc1[m][n][i], a3 = acc3[m][n][i];
                float h = (a1 / (1.f + expf(-a1))) * a3;
                char* hc = (char*)hbuf + ((size_t)rt * 64 + ct * 2 + (fl >> 6)) * ACH_B;
                *(ushort*)(hc + rl * 128 + ((2 * (fl & 63)) ^ sw)) = f2h_bits(h);
            }
        }
    }
}

// GEMM2: 128x128 tile, 4 waves, 2-buffer counted-vmcnt pipeline, atomic scatter
__global__ __launch_bounds__(256) void k_gemm2_t(const ushort* __restrict__ hbuf,
                                                 const ushort* __restrict__ W2h,
                                                 const int* __restrict__ texp,
                                                 const int* __restrict__ row_tok,
                                                 const float* __restrict__ row_w,
                                                 float* __restrict__ out) {
    __shared__ __align__(16) char lA[2][16384];
    __shared__ __align__(16) char lB[2][16384];
    int ct = blockIdx.x, rt = blockIdx.y;   // ct in [0,8): 128 cols of DM
    int e = texp[rt];
    const char* Ac = (const char*)hbuf + (size_t)rt * 64 * ACH_B;
    const char* Bc = (const char*)W2h + (size_t)((e * 16 + ct * 2) * 64) * CHUNK_B;
    int tid = threadIdx.x, lane = tid & 63, wv = tid >> 6;
    int wr = wv >> 1, wc = wv & 1;          // wave tile: 64 rows x 64 cols
    int bch = wv >> 1;
    int bin = (wv & 1) * 4096;

    const f32x4 fz = {0.f, 0.f, 0.f, 0.f};
    f32x4 acc[4][4];
#pragma unroll
    for (int m = 0; m < 4; m++)
#pragma unroll
        for (int n = 0; n < 4; n++) acc[m][n] = fz;

    // per wave per stage: 4 (A) + 4 (B) = 8 gll16
#define G2_STAGE(kt_, b_)                                                              \
    {                                                                                  \
        const char* As_ = Ac + (kt_) * ACH_B;                                          \
        _Pragma("unroll")                                                              \
        for (int i = 0; i < 4; i++)                                                    \
            gll16(As_ + wv * 4096 + i * 1024 + lane * 16, lA[b_] + wv * 4096 + i * 1024); \
        const char* Bs_ = Bc + (size_t)(bch * 64 + (kt_)) * CHUNK_B + bin;             \
        _Pragma("unroll")                                                              \
        for (int i = 0; i < 4; i++)                                                    \
            gll16(Bs_ + i * 1024 + lane * 16, lB[b_] + wv * 4096 + i * 1024);          \
    }

    G2_STAGE(0, 0);
    int cur = 0;
    for (int kt = 0; kt < 64; kt++) {
        if (kt < 63) {
            G2_STAGE(kt + 1, cur ^ 1);
            asm volatile("s_waitcnt vmcnt(8)" ::: "memory");
        } else {
            asm volatile("s_waitcnt vmcnt(0)" ::: "memory");
        }
        __syncthreads();
        __builtin_amdgcn_s_setprio(1);
#pragma unroll
        for (int ks = 0; ks < 2; ks++) {
            int kbyte = (ks * 32 + (lane >> 4) * 8) * 2;
            f16x8 af[4];
#pragma unroll
            for (int m = 0; m < 4; m++) {
                int r = wr * 64 + m * 16 + (lane & 15);
                af[m] = *(const f16x8*)(lA[cur] + r * 128 + (kbyte ^ ((r & 7) << 4)));
            }
#pragma unroll
            for (int n = 0; n < 4; n++) {
                int c = wc * 64 + n * 16 + (lane & 15);
                f16x8 b = *(const f16x8*)(lB[cur] + c * 128 + (kbyte ^ ((c & 7) << 4)));
#pragma unroll
                for (int m = 0; m < 4; m++) acc[m][n] = MFMA16(af[m], b, acc[m][n]);
            }
        }
        __builtin_amdgcn_s_setprio(0);
        __syncthreads();
        cur ^= 1;
    }
#undef G2_STAGE
    // epilogue: out[tok] += w * y (exactly 2 commutative adds per element)
    int cbase = ct * 128 + wc * 64;
#pragma unroll
    for (int m = 0; m < 4; m++) {
#pragma unroll
        for (int i = 0; i < 4; i++) {
            int rr = rt * BM + wr * 64 + m * 16 + (lane >> 4) * 4 + i;
            int tok = row_tok[rr];
            if (tok >= 0) {
                float w = row_w[rr];
                float* orow = out + (size_t)tok * DM + cbase + (lane & 15);
#pragma unroll
                for (int n = 0; n < 4; n++) atomicAdd(&orow[n * 16], w * acc[m][n][i]);
            }
        }
    }
}

extern "C" void kernel_launch(void* const* d_in, const int* in_sizes, int n_in,
                              void* d_out, int out_size, void* d_ws, size_t ws_size,
                              hipStream_t stream) {
    (void)in_sizes; (void)n_in; (void)out_size; (void)ws_size;
    const float* x  = (const float*)d_in[0];
    const float* Wr = (const float*)d_in[1];
    const float* W1 = (const float*)d_in[2];
    const float* W2 = (const float*)d_in[3];
    const float* W3 = (const float*)d_in[4];
    float* out = (float*)d_out;
    char* ws = (char*)d_ws;

    int* misc = (int*)ws;            // [cnt 8][fill 8][poff 8][texp 72]
    int* cnt  = misc;
    int* fill = misc + 8;
    int* poff = misc + 16;
    int* texp = misc + 24;
    int*    topi    = (int*)(ws + 1024);
    float*  topw    = (float*)(ws + 33792);
    float*  probs   = (float*)(ws + 66560);
    int*    row_tok = (int*)(ws + 197632);
    float*  row_w   = (float*)(ws + 234496);
    ushort* xg      = (ushort*)(ws + 271360);     // 18.9 MB
    ushort* hbuf    = (ushort*)(ws + 19145728);   // 75.5 MB
    ushort* W1h     = (ushort*)(ws + 94643200);   // 64 MB
    ushort* W3h     = (ushort*)(ws + 161752064);  // 64 MB
    ushort* W2h     = (ushort*)(ws + 228860928);  // 64 MB -> ends 295969792

    k_init<<<(T_TOK * DM + 1 + 255) / 256, 256, 0, stream>>>(out, misc, row_tok);
    k_router<<<T_TOK, 64, 0, stream>>>(x, Wr, probs, topi, topw, cnt);
    k_scan<<<1, 256, 0, stream>>>(probs, cnt, poff, texp, out + (size_t)T_TOK * DM);
    k_assign<<<(T_TOK + 255) / 256, 256, 0, stream>>>(topi, topw, poff, fill, row_tok, row_w);

    k_convert<<<dim3(16, 512), 256, 0, stream>>>(W1, W1h, DM);
    k_convert<<<dim3(16, 512), 256, 0, stream>>>(W3, W3h, DM);
    k_convert<<<dim3(64, 128), 256, 0, stream>>>(W2, W2h, DF);
    k_gather_t<<<dim3(16, MAXT), 256, 0, stream>>>(x, row_tok, xg);
    k_gemm1_t<<<dim3(32, MAXT), 512, 0, stream>>>(xg, W1h, W3h, texp, hbuf);
    k_gemm2_t<<<dim3(8, MAXT), 256, 0, stream>>>(hbuf, W2h, texp, row_tok, row_w, out);
}

// Round 5
// 710.286 us; speedup vs baseline: 1.0859x; 1.0859x over previous
//
#include <hip/hip_runtime.h>

#define T_TOK 4096
#define DM 1024
#define DF 4096
#define NE 8
#define BM 256
#define RCAP 10240      // 8192 + 8*256 worst-case padding
#define MAXT 40         // RCAP / BM
#define ACH_B 32768     // [256][64] fp16 swizzled A-chunk

typedef _Float16 f16x8 __attribute__((ext_vector_type(8)));
typedef float f32x4 __attribute__((ext_vector_type(4)));

#define MFMA16(a, b, c) __builtin_amdgcn_mfma_f32_16x16x32_f16(a, b, c, 0, 0, 0)

__device__ __forceinline__ ushort f2h_bits(float f) {
    _Float16 h = (_Float16)f;
    return __builtin_bit_cast(unsigned short, h);
}

__device__ __forceinline__ unsigned int pk2(float a, float b) {
    return __builtin_bit_cast(unsigned int, __builtin_amdgcn_cvt_pkrtz(a, b));
}

// async global->LDS, 16B per lane; lds ptr must be wave-uniform
__device__ __forceinline__ void gll16(const void* g, void* l) {
    __builtin_amdgcn_global_load_lds(
        (const __attribute__((address_space(1))) unsigned int*)g,
        (__attribute__((address_space(3))) unsigned int*)l, 16, 0, 0);
}

// ---------------- init ----------------
__global__ __launch_bounds__(256) void k_init(float* __restrict__ out,
                                              int* __restrict__ misc,
                                              int* __restrict__ row_tok) {
    int i = blockIdx.x * 256 + threadIdx.x;
    if (i < T_TOK * DM + 1) out[i] = 0.f;
    if (i < RCAP) row_tok[i] = -1;
    if (i < 256) misc[i] = 0;   // cnt[8], fill[8], poff[8], texp[40]
}

// ---------------- router ----------------
__global__ __launch_bounds__(64) void k_router(const float* __restrict__ x,
                                               const float* __restrict__ Wr,
                                               float* __restrict__ probs,
                                               int* __restrict__ topi,
                                               float* __restrict__ topw,
                                               int* __restrict__ cnt) {
    int t = blockIdx.x;
    int lane = threadIdx.x;
    const float* xr = x + (size_t)t * DM;
    float s[NE];
#pragma unroll
    for (int e = 0; e < NE; e++) s[e] = 0.f;
    for (int j = lane; j < DM; j += 64) {
        float xv = xr[j];
#pragma unroll
        for (int e = 0; e < NE; e++) s[e] += xv * Wr[e * DM + j];
    }
#pragma unroll
    for (int off = 32; off > 0; off >>= 1) {
#pragma unroll
        for (int e = 0; e < NE; e++) s[e] += __shfl_xor(s[e], off, 64);
    }
    if (lane == 0) {
        float mx = s[0];
#pragma unroll
        for (int e = 1; e < NE; e++) mx = fmaxf(mx, s[e]);
        float ex[NE], sum = 0.f;
#pragma unroll
        for (int e = 0; e < NE; e++) { ex[e] = expf(s[e] - mx); sum += ex[e]; }
        float inv = 1.f / sum;
        float p[NE];
#pragma unroll
        for (int e = 0; e < NE; e++) { p[e] = ex[e] * inv; probs[t * NE + e] = p[e]; }
        int i0 = 0;
#pragma unroll
        for (int e = 1; e < NE; e++) if (p[e] > p[i0]) i0 = e;
        int i1 = (i0 == 0) ? 1 : 0;
#pragma unroll
        for (int e = 0; e < NE; e++) if (e != i0 && p[e] > p[i1]) i1 = e;
        float w0 = p[i0], w1 = p[i1], winv = 1.f / (w0 + w1);
        topi[2 * t] = i0;     topw[2 * t] = w0 * winv;
        topi[2 * t + 1] = i1; topw[2 * t + 1] = w1 * winv;
        atomicAdd(&cnt[i0], 1);
        atomicAdd(&cnt[i1], 1);
    }
}

// ---------------- scan ----------------
__global__ __launch_bounds__(256) void k_scan(const float* __restrict__ probs,
                                              const int* __restrict__ cnt,
                                              int* __restrict__ poff,
                                              int* __restrict__ texp,
                                              float* __restrict__ aux_out) {
    __shared__ float red[256 * NE];
    int tid = threadIdx.x;
    float part[NE];
#pragma unroll
    for (int e = 0; e < NE; e++) part[e] = 0.f;
    for (int t = tid; t < T_TOK; t += 256) {
#pragma unroll
        for (int e = 0; e < NE; e++) part[e] += probs[t * NE + e];
    }
#pragma unroll
    for (int e = 0; e < NE; e++) red[tid * NE + e] = part[e];
    __syncthreads();
    for (int s2 = 128; s2 > 0; s2 >>= 1) {
        if (tid < s2) {
#pragma unroll
            for (int e = 0; e < NE; e++) red[tid * NE + e] += red[(tid + s2) * NE + e];
        }
        __syncthreads();
    }
    if (tid == 0) {
        float al = 0.f;
#pragma unroll
        for (int e = 0; e < NE; e++) al += red[e] * (float)cnt[e];
        *aux_out = al * (8.0f / (16777216.0f + 1e-6f));
        int run = 0, tix = 0;
        for (int e = 0; e < NE; e++) {
            poff[e] = run;
            int nt = (cnt[e] + BM - 1) / BM;
            for (int i = 0; i < nt; i++) texp[tix++] = e;
            run += nt * BM;
        }
    }
}

// ---------------- assign ----------------
__global__ __launch_bounds__(256) void k_assign(const int* __restrict__ topi,
                                                const float* __restrict__ topw,
                                                const int* __restrict__ poff,
                                                int* __restrict__ fill,
                                                int* __restrict__ row_tok,
                                                float* __restrict__ row_w) {
    int t = blockIdx.x * 256 + threadIdx.x;
    if (t >= T_TOK) return;
#pragma unroll
    for (int k = 0; k < 2; k++) {
        int e = topi[2 * t + k];
        int pos = atomicAdd(&fill[e], 1);
        int r = poff[e] + pos;
        row_tok[r] = t;
        row_w[r] = topw[2 * t + k];
    }
}

// gather x rows into tile-ordered swizzled fp16: chunk (rt, kt) = [256][64]
__global__ __launch_bounds__(512) void k_gather_t(const float* __restrict__ x,
                                                  const int* __restrict__ row_tok,
                                                  ushort* __restrict__ xg) {
    int kt = blockIdx.x, rt = blockIdx.y;
    int tid = threadIdx.x;
    int r = tid >> 1, c0 = (tid & 1) * 32;
    int tok = row_tok[rt * BM + r];
    char* chunk = (char*)xg + ((size_t)rt * 16 + kt) * ACH_B;
    int sw = (r & 7) << 4;
    if (tok >= 0) {
        const float* s = x + (size_t)tok * DM + kt * 64 + c0;
#pragma unroll
        for (int j = 0; j < 4; j++) {
            float4 va = *(const float4*)(s + j * 8);
            float4 vb = *(const float4*)(s + j * 8 + 4);
            uint4 u = {pk2(va.x, va.y), pk2(va.z, va.w), pk2(vb.x, vb.y), pk2(vb.z, vb.w)};
            *(uint4*)(chunk + r * 128 + ((c0 * 2 + j * 16) ^ sw)) = u;
        }
    } else {
        uint4 z = {0, 0, 0, 0};
#pragma unroll
        for (int j = 0; j < 4; j++)
            *(uint4*)(chunk + r * 128 + ((c0 * 2 + j * 16) ^ sw)) = z;
    }
}

// GEMM1: 256x128 fused dual-B, 8 waves (4Mx2N, wave 64x64), 2-phase pipeline,
// A via global_load_lds from pre-swizzled fp16, B reg-staged fp32->fp16.
__global__ __launch_bounds__(512, 2) void k_g1(const ushort* __restrict__ xg,
                                               const float* __restrict__ W1,
                                               const float* __restrict__ W3,
                                               const int* __restrict__ texp,
                                               ushort* __restrict__ hbuf) {
    __shared__ __align__(16) char lA[2][32768];   // [256][64] fp16 swz
    __shared__ __align__(16) char lB1[2][16384];  // [128][64] fp16 swz
    __shared__ __align__(16) char lB3[2][16384];
    int b = blockIdx.x;
    int swz = (b & 7) * 160 + (b >> 3);           // XCD-bijective, ct-major stripes
    int ct = swz / MAXT, rt = swz % MAXT;         // ct in [0,32)
    int e = texp[rt];
    int tid = threadIdx.x, lane = tid & 63, wv = tid >> 6;
    int wr = wv >> 1, wc = wv & 1;

    const char* Ac = (const char*)xg + (size_t)rt * 16 * ACH_B;
    // B staging: wave wv covers rows [wv*16, wv*16+16) of the 128-row slice
    int lrow = lane >> 2, lcol = (lane & 3) * 16;
    int brow = wv * 16 + lrow;
    const float* B1g = W1 + ((size_t)e * DF + ct * 128 + brow) * DM + lcol;
    const float* B3g = W3 + ((size_t)e * DF + ct * 128 + brow) * DM + lcol;
    int xw = (brow & 7) << 4;
    int wb0 = brow * 128 + ((lcol * 2) ^ xw);
    int wb1 = brow * 128 + ((lcol * 2 + 16) ^ xw);

    const f32x4 fz = {0.f, 0.f, 0.f, 0.f};
    f32x4 acc1[4][4], acc3[4][4];
#pragma unroll
    for (int m = 0; m < 4; m++)
#pragma unroll
        for (int n = 0; n < 4; n++) { acc1[m][n] = fz; acc3[m][n] = fz; }

    float4 rb1[4], rb3[4];

#define G1_LOADB(kt_)                                                   \
    {                                                                   \
        const float* p1 = B1g + (kt_) * 64;                             \
        rb1[0] = *(const float4*)(p1);                                  \
        rb1[1] = *(const float4*)(p1 + 4);                              \
        rb1[2] = *(const float4*)(p1 + 8);                              \
        rb1[3] = *(const float4*)(p1 + 12);                             \
        const float* p3 = B3g + (kt_) * 64;                             \
        rb3[0] = *(const float4*)(p3);                                  \
        rb3[1] = *(const float4*)(p3 + 4);                              \
        rb3[2] = *(const float4*)(p3 + 8);                              \
        rb3[3] = *(const float4*)(p3 + 12);                             \
    }

#define G1_LOADA(kt_, b_)                                                              \
    {                                                                                  \
        const char* As_ = Ac + (kt_) * ACH_B;                                          \
        _Pragma("unroll")                                                              \
        for (int i = 0; i < 4; i++)                                                    \
            gll16(As_ + wv * 4096 + i * 1024 + lane * 16, lA[b_] + wv * 4096 + i * 1024); \
    }

#define G1_WRITEB(b_)                                                                  \
    {                                                                                  \
        uint4 u0 = {pk2(rb1[0].x, rb1[0].y), pk2(rb1[0].z, rb1[0].w),                  \
                    pk2(rb1[1].x, rb1[1].y), pk2(rb1[1].z, rb1[1].w)};                 \
        uint4 u1 = {pk2(rb1[2].x, rb1[2].y), pk2(rb1[2].z, rb1[2].w),                  \
                    pk2(rb1[3].x, rb1[3].y), pk2(rb1[3].z, rb1[3].w)};                 \
        *(uint4*)(lB1[b_] + wb0) = u0;                                                 \
        *(uint4*)(lB1[b_] + wb1) = u1;                                                 \
        uint4 v0 = {pk2(rb3[0].x, rb3[0].y), pk2(rb3[0].z, rb3[0].w),                  \
                    pk2(rb3[1].x, rb3[1].y), pk2(rb3[1].z, rb3[1].w)};                 \
        uint4 v1 = {pk2(rb3[2].x, rb3[2].y), pk2(rb3[2].z, rb3[2].w),                  \
                    pk2(rb3[3].x, rb3[3].y), pk2(rb3[3].z, rb3[3].w)};                 \
        *(uint4*)(lB3[b_] + wb0) = v0;                                                 \
        *(uint4*)(lB3[b_] + wb1) = v1;                                                 \
    }

    // prologue: tile 0
    G1_LOADB(0);
    G1_LOADA(0, 0);
    G1_WRITEB(0);
    asm volatile("s_waitcnt vmcnt(0)" ::: "memory");
    __syncthreads();

    int cur = 0;
    for (int kt = 0; kt < 16; kt++) {
        if (kt < 15) {
            G1_LOADB(kt + 1);
            G1_LOADA(kt + 1, cur ^ 1);
        }
        const char* cA = lA[cur];
        const char* cB1 = lB1[cur];
        const char* cB3 = lB3[cur];
        __builtin_amdgcn_s_setprio(1);
#pragma unroll
        for (int ks = 0; ks < 2; ks++) {
            int kbyte = (ks * 32 + (lane >> 4) * 8) * 2;
            f16x8 af[4];
#pragma unroll
            for (int m = 0; m < 4; m++) {
                int r = wr * 64 + m * 16 + (lane & 15);
                af[m] = *(const f16x8*)(cA + r * 128 + (kbyte ^ ((r & 7) << 4)));
            }
#pragma unroll
            for (int n = 0; n < 4; n++) {
                int c = wc * 64 + n * 16 + (lane & 15);
                int off = c * 128 + (kbyte ^ ((c & 7) << 4));
                f16x8 b1 = *(const f16x8*)(cB1 + off);
                f16x8 b3 = *(const f16x8*)(cB3 + off);
#pragma unroll
                for (int m = 0; m < 4; m++) {
                    acc1[m][n] = MFMA16(af[m], b1, acc1[m][n]);
                    acc3[m][n] = MFMA16(af[m], b3, acc3[m][n]);
                }
            }
        }
        __builtin_amdgcn_s_setprio(0);
        if (kt < 15) G1_WRITEB(cur ^ 1);   // compiler waits the B loads
        asm volatile("s_waitcnt vmcnt(0)" ::: "memory");
        __syncthreads();
        cur ^= 1;
    }
#undef G1_LOADB
#undef G1_LOADA
#undef G1_WRITEB

    // epilogue: silu(a1)*a3 -> hbuf chunks (rt, ct*2 + fl/64), swizzled fp16
#pragma unroll
    for (int m = 0; m < 4; m++) {
#pragma unroll
        for (int i = 0; i < 4; i++) {
            int rl = wr * 64 + m * 16 + (lane >> 4) * 4 + i;   // 0..255
            int sw = (rl & 7) << 4;
#pragma unroll
            for (int n = 0; n < 4; n++) {
                int fl = wc * 64 + n * 16 + (lane & 15);        // 0..127
                float a1 = acc1[m][n][i], a3 = acc3[m][n][i];
                float h = (a1 / (1.f + expf(-a1))) * a3;
                char* hc = (char*)hbuf + ((size_t)rt * 64 + ct * 2 + (fl >> 6)) * ACH_B;
                *(ushort*)(hc + rl * 128 + ((2 * (fl & 63)) ^ sw)) = f2h_bits(h);
            }
        }
    }
}

// GEMM2: 256x128, 8 waves (4Mx2N, wave 64x64), same pipeline, atomic scatter
__global__ __launch_bounds__(512, 2) void k_g2(const ushort* __restrict__ hbuf,
                                               const float* __restrict__ W2,
                                               const int* __restrict__ texp,
                                               const int* __restrict__ row_tok,
                                               const float* __restrict__ row_w,
                                               float* __restrict__ out) {
    __shared__ __align__(16) char lA[2][32768];   // [256][64] fp16 swz
    __shared__ __align__(16) char lB[2][16384];   // [128][64] fp16 swz
    int b = blockIdx.x;
    int swz = (b & 7) * MAXT + (b >> 3);          // 320 = 8*40, ct per XCD
    int ct = swz / MAXT, rt = swz % MAXT;         // ct in [0,8)
    int e = texp[rt];
    int tid = threadIdx.x, lane = tid & 63, wv = tid >> 6;
    int wr = wv >> 1, wc = wv & 1;

    const char* Ac = (const char*)hbuf + (size_t)rt * 64 * ACH_B;
    int lrow = lane >> 2, lcol = (lane & 3) * 16;
    int brow = wv * 16 + lrow;
    const float* Bg = W2 + ((size_t)e * DM + ct * 128 + brow) * DF + lcol;
    int xw = (brow & 7) << 4;
    int wb0 = brow * 128 + ((lcol * 2) ^ xw);
    int wb1 = brow * 128 + ((lcol * 2 + 16) ^ xw);

    const f32x4 fz = {0.f, 0.f, 0.f, 0.f};
    f32x4 acc[4][4];
#pragma unroll
    for (int m = 0; m < 4; m++)
#pragma unroll
        for (int n = 0; n < 4; n++) acc[m][n] = fz;

    float4 rb[4];

#define G2_LOADB(kt_)                                                   \
    {                                                                   \
        const float* p = Bg + (kt_) * 64;                               \
        rb[0] = *(const float4*)(p);                                    \
        rb[1] = *(const float4*)(p + 4);                                \
        rb[2] = *(const float4*)(p + 8);                                \
        rb[3] = *(const float4*)(p + 12);                               \
    }

#define G2_LOADA(kt_, b_)                                                              \
    {                                                                                  \
        const char* As_ = Ac + (kt_) * ACH_B;                                          \
        _Pragma("unroll")                                                              \
        for (int i = 0; i < 4; i++)                                                    \
            gll16(As_ + wv * 4096 + i * 1024 + lane * 16, lA[b_] + wv * 4096 + i * 1024); \
    }

#define G2_WRITEB(b_)                                                                  \
    {                                                                                  \
        uint4 u0 = {pk2(rb[0].x, rb[0].y), pk2(rb[0].z, rb[0].w),                      \
                    pk2(rb[1].x, rb[1].y), pk2(rb[1].z, rb[1].w)};                     \
        uint4 u1 = {pk2(rb[2].x, rb[2].y), pk2(rb[2].z, rb[2].w),                      \
                    pk2(rb[3].x, rb[3].y), pk2(rb[3].z, rb[3].w)};                     \
        *(uint4*)(lB[b_] + wb0) = u0;                                                  \
        *(uint4*)(lB[b_] + wb1) = u1;                                                  \
    }

    G2_LOADB(0);
    G2_LOADA(0, 0);
    G2_WRITEB(0);
    asm volatile("s_waitcnt vmcnt(0)" ::: "memory");
    __syncthreads();

    int cur = 0;
    for (int kt = 0; kt < 64; kt++) {
        if (kt < 63) {
            G2_LOADB(kt + 1);
            G2_LOADA(kt + 1, cur ^ 1);
        }
        const char* cA = lA[cur];
        const char* cB = lB[cur];
        __builtin_amdgcn_s_setprio(1);
#pragma unroll
        for (int ks = 0; ks < 2; ks++) {
            int kbyte = (ks * 32 + (lane >> 4) * 8) * 2;
            f16x8 af[4];
#pragma unroll
            for (int m = 0; m < 4; m++) {
                int r = wr * 64 + m * 16 + (lane & 15);
                af[m] = *(const f16x8*)(cA + r * 128 + (kbyte ^ ((r & 7) << 4)));
            }
#pragma unroll
            for (int n = 0; n < 4; n++) {
                int c = wc * 64 + n * 16 + (lane & 15);
                f16x8 bf = *(const f16x8*)(cB + c * 128 + (kbyte ^ ((c & 7) << 4)));
#pragma unroll
                for (int m = 0; m < 4; m++) acc[m][n] = MFMA16(af[m], bf, acc[m][n]);
            }
        }
        __builtin_amdgcn_s_setprio(0);
        if (kt < 63) G2_WRITEB(cur ^ 1);
        asm volatile("s_waitcnt vmcnt(0)" ::: "memory");
        __syncthreads();
        cur ^= 1;
    }
#undef G2_LOADB
#undef G2_LOADA
#undef G2_WRITEB

    // epilogue: out[tok] += w * y (exactly 2 commutative adds per element)
#pragma unroll
    for (int m = 0; m < 4; m++) {
#pragma unroll
        for (int i = 0; i < 4; i++) {
            int rr = rt * BM + wr * 64 + m * 16 + (lane >> 4) * 4 + i;
            int tok = row_tok[rr];
            if (tok >= 0) {
                float w = row_w[rr];
                float* orow = out + (size_t)tok * DM + ct * 128 + wc * 64 + (lane & 15);
#pragma unroll
                for (int n = 0; n < 4; n++) atomicAdd(&orow[n * 16], w * acc[m][n][i]);
            }
        }
    }
}

extern "C" void kernel_launch(void* const* d_in, const int* in_sizes, int n_in,
                              void* d_out, int out_size, void* d_ws, size_t ws_size,
                              hipStream_t stream) {
    (void)in_sizes; (void)n_in; (void)out_size; (void)ws_size;
    const float* x  = (const float*)d_in[0];
    const float* Wr = (const float*)d_in[1];
    const float* W1 = (const float*)d_in[2];
    const float* W2 = (const float*)d_in[3];
    const float* W3 = (const float*)d_in[4];
    float* out = (float*)d_out;
    char* ws = (char*)d_ws;

    int* misc = (int*)ws;            // [cnt 8][fill 8][poff 8][texp 40]
    int* cnt  = misc;
    int* fill = misc + 8;
    int* poff = misc + 16;
    int* texp = misc + 24;
    int*    topi    = (int*)(ws + 1024);
    float*  topw    = (float*)(ws + 33792);
    float*  probs   = (float*)(ws + 66560);
    int*    row_tok = (int*)(ws + 197632);      // RCAP ints
    float*  row_w   = (float*)(ws + 238592);    // RCAP floats
    ushort* xg      = (ushort*)(ws + 279552);   // 40*16 chunks of 32KB = 20 MB
    ushort* hbuf    = (ushort*)(ws + 21251072); // 40*64 chunks of 32KB = 80 MB

    k_init<<<(T_TOK * DM + 1 + 255) / 256, 256, 0, stream>>>(out, misc, row_tok);
    k_router<<<T_TOK, 64, 0, stream>>>(x, Wr, probs, topi, topw, cnt);
    k_scan<<<1, 256, 0, stream>>>(probs, cnt, poff, texp, out + (size_t)T_TOK * DM);
    k_assign<<<(T_TOK + 255) / 256, 256, 0, stream>>>(topi, topw, poff, fill, row_tok, row_w);
    k_gather_t<<<dim3(16, MAXT), 512, 0, stream>>>(x, row_tok, xg);
    k_g1<<<32 * MAXT, 512, 0, stream>>>(xg, W1, W3, texp, hbuf);
    k_g2<<<8 * MAXT, 512, 0, stream>>>(hbuf, W2, texp, row_tok, row_w, out);
}

// Round 6
// 642.478 us; speedup vs baseline: 1.2006x; 1.1055x over previous
//
#include <hip/hip_runtime.h>

#define T_TOK 4096
#define DM 1024
#define DF 4096
#define NE 8
#define BM 256
#define RCAP 10240      // 8192 + 8*256 worst-case padding
#define MAXT 40         // RCAP / BM (256-row tiles)
#define MAXT2 80        // RCAP / 128 (128-row tiles, gemm2)
#define ACH_B 32768     // [256][64] fp16 swizzled A-chunk
#define CHUNK_B 8192    // [64][64] fp16 swizzled weight chunk

typedef _Float16 f16x8 __attribute__((ext_vector_type(8)));
typedef float f32x4 __attribute__((ext_vector_type(4)));

#define MFMA16(a, b, c) __builtin_amdgcn_mfma_f32_16x16x32_f16(a, b, c, 0, 0, 0)
#define RAW_BAR() __builtin_amdgcn_s_barrier()
#define VMCNT(n) asm volatile("s_waitcnt vmcnt(" #n ")" ::: "memory")

__device__ __forceinline__ ushort f2h_bits(float f) {
    _Float16 h = (_Float16)f;
    return __builtin_bit_cast(unsigned short, h);
}

__device__ __forceinline__ unsigned int pk2(float a, float b) {
    return __builtin_bit_cast(unsigned int, __builtin_amdgcn_cvt_pkrtz(a, b));
}

__device__ __forceinline__ uint4 pack8(float4 a, float4 b) {
    uint4 r;
    r.x = pk2(a.x, a.y); r.y = pk2(a.z, a.w);
    r.z = pk2(b.x, b.y); r.w = pk2(b.z, b.w);
    return r;
}

// async global->LDS, 16B per lane; lds ptr wave-uniform
__device__ __forceinline__ void gll16(const void* g, void* l) {
    __builtin_amdgcn_global_load_lds(
        (const __attribute__((address_space(1))) unsigned int*)g,
        (__attribute__((address_space(3))) unsigned int*)l, 16, 0, 0);
}

// ---------------- init ----------------
__global__ __launch_bounds__(256) void k_init(float* __restrict__ out,
                                              int* __restrict__ misc,
                                              int* __restrict__ row_tok) {
    int i = blockIdx.x * 256 + threadIdx.x;
    if (i < T_TOK * DM + 1) out[i] = 0.f;
    if (i < RCAP) row_tok[i] = -1;
    if (i < 256) misc[i] = 0;   // cnt8 fill8 poff8 texp40 texp2(80)
}

// ---------------- router ----------------
__global__ __launch_bounds__(64) void k_router(const float* __restrict__ x,
                                               const float* __restrict__ Wr,
                                               float* __restrict__ probs,
                                               int* __restrict__ topi,
                                               float* __restrict__ topw,
                                               int* __restrict__ cnt) {
    int t = blockIdx.x;
    int lane = threadIdx.x;
    const float* xr = x + (size_t)t * DM;
    float s[NE];
#pragma unroll
    for (int e = 0; e < NE; e++) s[e] = 0.f;
    for (int j = lane; j < DM; j += 64) {
        float xv = xr[j];
#pragma unroll
        for (int e = 0; e < NE; e++) s[e] += xv * Wr[e * DM + j];
    }
#pragma unroll
    for (int off = 32; off > 0; off >>= 1) {
#pragma unroll
        for (int e = 0; e < NE; e++) s[e] += __shfl_xor(s[e], off, 64);
    }
    if (lane == 0) {
        float mx = s[0];
#pragma unroll
        for (int e = 1; e < NE; e++) mx = fmaxf(mx, s[e]);
        float ex[NE], sum = 0.f;
#pragma unroll
        for (int e = 0; e < NE; e++) { ex[e] = expf(s[e] - mx); sum += ex[e]; }
        float inv = 1.f / sum;
        float p[NE];
#pragma unroll
        for (int e = 0; e < NE; e++) { p[e] = ex[e] * inv; probs[t * NE + e] = p[e]; }
        int i0 = 0;
#pragma unroll
        for (int e = 1; e < NE; e++) if (p[e] > p[i0]) i0 = e;
        int i1 = (i0 == 0) ? 1 : 0;
#pragma unroll
        for (int e = 0; e < NE; e++) if (e != i0 && p[e] > p[i1]) i1 = e;
        float w0 = p[i0], w1 = p[i1], winv = 1.f / (w0 + w1);
        topi[2 * t] = i0;     topw[2 * t] = w0 * winv;
        topi[2 * t + 1] = i1; topw[2 * t + 1] = w1 * winv;
        atomicAdd(&cnt[i0], 1);
        atomicAdd(&cnt[i1], 1);
    }
}

// ---------------- scan ----------------
__global__ __launch_bounds__(256) void k_scan(const float* __restrict__ probs,
                                              const int* __restrict__ cnt,
                                              int* __restrict__ poff,
                                              int* __restrict__ texp,
                                              int* __restrict__ texp2,
                                              float* __restrict__ aux_out) {
    __shared__ float red[256 * NE];
    int tid = threadIdx.x;
    float part[NE];
#pragma unroll
    for (int e = 0; e < NE; e++) part[e] = 0.f;
    for (int t = tid; t < T_TOK; t += 256) {
#pragma unroll
        for (int e = 0; e < NE; e++) part[e] += probs[t * NE + e];
    }
#pragma unroll
    for (int e = 0; e < NE; e++) red[tid * NE + e] = part[e];
    __syncthreads();
    for (int s2 = 128; s2 > 0; s2 >>= 1) {
        if (tid < s2) {
#pragma unroll
            for (int e = 0; e < NE; e++) red[tid * NE + e] += red[(tid + s2) * NE + e];
        }
        __syncthreads();
    }
    if (tid == 0) {
        float al = 0.f;
#pragma unroll
        for (int e = 0; e < NE; e++) al += red[e] * (float)cnt[e];
        *aux_out = al * (8.0f / (16777216.0f + 1e-6f));
        int run = 0, tix = 0;
        for (int e = 0; e < NE; e++) {
            poff[e] = run;
            int nt = (cnt[e] + BM - 1) / BM;
            for (int i = 0; i < nt; i++) texp[tix++] = e;
            run += nt * BM;
        }
        for (int j = 0; j < MAXT2; j++) texp2[j] = texp[j >> 1];
    }
}

// ---------------- assign ----------------
__global__ __launch_bounds__(256) void k_assign(const int* __restrict__ topi,
                                                const float* __restrict__ topw,
                                                const int* __restrict__ poff,
                                                int* __restrict__ fill,
                                                int* __restrict__ row_tok,
                                                float* __restrict__ row_w) {
    int t = blockIdx.x * 256 + threadIdx.x;
    if (t >= T_TOK) return;
#pragma unroll
    for (int k = 0; k < 2; k++) {
        int e = topi[2 * t + k];
        int pos = atomicAdd(&fill[e], 1);
        int r = poff[e] + pos;
        row_tok[r] = t;
        row_w[r] = topw[2 * t + k];
    }
}

// convert fp32 [rows][row_len] -> tile-ordered swizzled fp16 64x64 chunks
__global__ __launch_bounds__(256) void k_convert(const float* __restrict__ src,
                                                 ushort* __restrict__ dst,
                                                 int row_len) {
    int nk = row_len >> 6;
    int kt = blockIdx.x, rt = blockIdx.y;
    int tid = threadIdx.x;
    int r = tid >> 2, c0 = (tid & 3) * 16;
    const float* s = src + (size_t)(rt * 64 + r) * row_len + kt * 64 + c0;
    float4 v0 = *(const float4*)(s);
    float4 v1 = *(const float4*)(s + 4);
    float4 v2 = *(const float4*)(s + 8);
    float4 v3 = *(const float4*)(s + 12);
    char* chunk = (char*)dst + ((size_t)rt * nk + kt) * CHUNK_B;
    int sw = (r & 7) << 4;
    *(uint4*)(chunk + r * 128 + ((2 * c0) ^ sw)) = pack8(v0, v1);
    *(uint4*)(chunk + r * 128 + ((2 * c0 + 16) ^ sw)) = pack8(v2, v3);
}

// gather x rows into [256][64] swizzled fp16 chunks (rt, kt)
__global__ __launch_bounds__(512) void k_gather_t(const float* __restrict__ x,
                                                  const int* __restrict__ row_tok,
                                                  ushort* __restrict__ xg) {
    int kt = blockIdx.x, rt = blockIdx.y;
    int tid = threadIdx.x;
    int r = tid >> 1, c0 = (tid & 1) * 32;
    int tok = row_tok[rt * BM + r];
    char* chunk = (char*)xg + ((size_t)rt * 16 + kt) * ACH_B;
    int sw = (r & 7) << 4;
    if (tok >= 0) {
        const float* s = x + (size_t)tok * DM + kt * 64 + c0;
#pragma unroll
        for (int j = 0; j < 4; j++) {
            float4 va = *(const float4*)(s + j * 8);
            float4 vb = *(const float4*)(s + j * 8 + 4);
            *(uint4*)(chunk + r * 128 + ((c0 * 2 + j * 16) ^ sw)) = pack8(va, vb);
        }
    } else {
        uint4 z = {0, 0, 0, 0};
#pragma unroll
        for (int j = 0; j < 4; j++)
            *(uint4*)(chunk + r * 128 + ((c0 * 2 + j * 16) ^ sw)) = z;
    }
}

// ============ GEMM1: 256 rows x 128 f-cols, dual-B, 8-phase ring-2 ============
__global__ __launch_bounds__(512, 2) void k_g1(const ushort* __restrict__ xg,
                                               const ushort* __restrict__ W1h,
                                               const ushort* __restrict__ W3h,
                                               const int* __restrict__ texp,
                                               ushort* __restrict__ hbuf) {
    __shared__ __align__(16) char lds[131072];  // buf b: A at b*65536, B1 +32768, B3 +49152
    int b = blockIdx.x;
    int sz = (b & 7) * 160 + (b >> 3);          // bijective (1280 = 8*160)
    int ct = sz / MAXT, rt = sz % MAXT;         // ct in [0,32)
    int e = texp[rt];
    int tid = threadIdx.x, lane = tid & 63, wv = tid >> 6;
    int wr = wv >> 1, wc = wv & 1;

    const char* Ac  = (const char*)xg + (size_t)rt * 16 * ACH_B;
    const char* B1c = (const char*)W1h + ((size_t)(e * 64 + ct * 2) * 16) * CHUNK_B;
    const char* B3c = (const char*)W3h + ((size_t)(e * 64 + ct * 2) * 16) * CHUNK_B;

    const f32x4 fz = {0.f, 0.f, 0.f, 0.f};
    f32x4 acc1[4][4], acc3[4][4];
#pragma unroll
    for (int m = 0; m < 4; m++)
#pragma unroll
        for (int n = 0; n < 4; n++) { acc1[m][n] = fz; acc3[m][n] = fz; }

    f16x8 af[4], bf[4];
    int kb_base = (lane >> 4) * 16;

    // stage one 16KB A-half (2 loads/lane)
#define ST_A(kt_, b_, h_) {                                                        \
        const char* s_ = Ac + (kt_) * ACH_B + (h_) * 16384 + wv * 2048 + lane * 16; \
        char* d_ = lds + (b_) * 65536 + (h_) * 16384 + wv * 2048;                   \
        gll16(s_, d_); gll16(s_ + 1024, d_ + 1024); }
    // stage one 16KB B unit = two 8KB chunks (2 loads/lane)
#define ST_B(Bc_, kt_, b_, off_) {                                                          \
        gll16(Bc_ + (kt_) * 8192 + wv * 1024 + lane * 16,                                    \
              lds + (b_) * 65536 + (off_) + wv * 1024);                                      \
        gll16(Bc_ + 131072 + (kt_) * 8192 + wv * 1024 + lane * 16,                           \
              lds + (b_) * 65536 + (off_) + 8192 + wv * 1024); }
    // ds-read fragments
#define DS_A(b_, ks_) _Pragma("unroll") for (int m = 0; m < 4; m++) {              \
        int r_ = wr * 64 + m * 16 + (lane & 15);                                   \
        af[m] = *(const f16x8*)(lds + (b_) * 65536 + r_ * 128 +                    \
                                 (((ks_) * 64 + kb_base) ^ ((r_ & 7) << 4))); }
#define DS_B(b_, off_, ks_) _Pragma("unroll") for (int n = 0; n < 4; n++) {        \
        int c_ = wc * 64 + n * 16 + (lane & 15);                                   \
        bf[n] = *(const f16x8*)(lds + (b_) * 65536 + (off_) + c_ * 128 +           \
                                 (((ks_) * 64 + kb_base) ^ ((c_ & 7) << 4))); }
#define MM(accX) _Pragma("unroll") for (int n = 0; n < 4; n++)                     \
        _Pragma("unroll") for (int m = 0; m < 4; m++)                              \
            accX[m][n] = MFMA16(af[m], bf[n], accX[m][n]);

    // prologue: stage X(=buf0) with K-tile 0
    ST_A(0, 0, 0); ST_A(0, 0, 1); ST_B(B1c, 0, 0, 32768); ST_B(B3c, 0, 0, 49152);
    VMCNT(2);           // A+B1 landed, B3 may fly
    RAW_BAR();

    for (int it = 0; it < 8; ++it) {
        int t1 = 2 * it + 1;
        int t2 = 2 * it + 2;
        // ph1: X ks0 W1   | stage Y A-h0 <- t1
        DS_A(0, 0); DS_B(0, 32768, 0);
        ST_A(t1, 1, 0);
        RAW_BAR();
        __builtin_amdgcn_s_setprio(1); MM(acc1); __builtin_amdgcn_s_setprio(0);
        VMCNT(2);       // forces X-B3 (needed ph2)
        RAW_BAR();
        // ph2: X ks0 W3   | stage Y A-h1
        DS_B(0, 49152, 0);
        ST_A(t1, 1, 1);
        RAW_BAR();
        __builtin_amdgcn_s_setprio(1); MM(acc3); __builtin_amdgcn_s_setprio(0);
        RAW_BAR();
        // ph3: X ks1 W1   | stage Y B1
        DS_A(0, 1); DS_B(0, 32768, 1);
        ST_B(B1c, t1, 1, 32768);
        RAW_BAR();
        __builtin_amdgcn_s_setprio(1); MM(acc1); __builtin_amdgcn_s_setprio(0);
        RAW_BAR();
        // ph4: X ks1 W3   | stage Y B3
        DS_B(0, 49152, 1);
        ST_B(B3c, t1, 1, 49152);
        RAW_BAR();
        __builtin_amdgcn_s_setprio(1); MM(acc3); __builtin_amdgcn_s_setprio(0);
        VMCNT(2);       // forces Y A-h0,A-h1,B1 (needed ph5)
        RAW_BAR();
        // ph5: Y ks0 W1   | stage X' A-h0 <- t2
        DS_A(1, 0); DS_B(1, 32768, 0);
        if (it < 7) ST_A(t2, 0, 0);
        RAW_BAR();
        __builtin_amdgcn_s_setprio(1); MM(acc1); __builtin_amdgcn_s_setprio(0);
        if (it < 7) { VMCNT(2); } else { VMCNT(0); }   // forces Y-B3 (needed ph6)
        RAW_BAR();
        // ph6: Y ks0 W3   | stage X' A-h1
        DS_B(1, 49152, 0);
        if (it < 7) ST_A(t2, 0, 1);
        RAW_BAR();
        __builtin_amdgcn_s_setprio(1); MM(acc3); __builtin_amdgcn_s_setprio(0);
        RAW_BAR();
        // ph7: Y ks1 W1   | stage X' B1
        DS_A(1, 1); DS_B(1, 32768, 1);
        if (it < 7) ST_B(B1c, t2, 0, 32768);
        RAW_BAR();
        __builtin_amdgcn_s_setprio(1); MM(acc1); __builtin_amdgcn_s_setprio(0);
        RAW_BAR();
        // ph8: Y ks1 W3   | stage X' B3
        DS_B(1, 49152, 1);
        if (it < 7) ST_B(B3c, t2, 0, 49152);
        RAW_BAR();
        __builtin_amdgcn_s_setprio(1); MM(acc3); __builtin_amdgcn_s_setprio(0);
        if (it < 7) { VMCNT(2); }   // forces X' A+B1 (needed next ph1)
        RAW_BAR();
    }
#undef ST_A
#undef ST_B
#undef DS_A
#undef DS_B
#undef MM

    // epilogue: silu(a1)*a3 -> hbuf chunks (rt, ct*2 + fl/64), swizzled fp16
#pragma unroll
    for (int m = 0; m < 4; m++) {
#pragma unroll
        for (int i = 0; i < 4; i++) {
            int rl = wr * 64 + m * 16 + (lane >> 4) * 4 + i;   // 0..255
            int sw = (rl & 7) << 4;
#pragma unroll
            for (int n = 0; n < 4; n++) {
                int fl = wc * 64 + n * 16 + (lane & 15);        // 0..127
                float a1 = acc1[m][n][i], a3 = acc3[m][n][i];
                float h = (a1 / (1.f + expf(-a1))) * a3;
                char* hc = (char*)hbuf + ((size_t)rt * 64 + ct * 2 + (fl >> 6)) * ACH_B;
                *(ushort*)(hc + rl * 128 + ((2 * (fl & 63)) ^ sw)) = f2h_bits(h);
            }
        }
    }
}

// ============ GEMM2: 128x128, 4 waves, 2-ring, 2 blocks/CU ============
__global__ __launch_bounds__(256, 2) void k_g2(const ushort* __restrict__ hbuf,
                                               const ushort* __restrict__ W2h,
                                               const int* __restrict__ texp2,
                                               const int* __restrict__ row_tok,
                                               const float* __restrict__ row_w,
                                               float* __restrict__ out) {
    __shared__ __align__(16) char lds[65536];   // buf b: A at b*32768, B +16384
    int b = blockIdx.x;
    int sz = (b & 7) * 80 + (b >> 3);           // bijective (640 = 8*80)
    int ct = sz / MAXT2, rt2 = sz % MAXT2;      // ct in [0,8)
    int e = texp2[rt2];
    int tid = threadIdx.x, lane = tid & 63, wv = tid >> 6;
    int wr = wv >> 1, wc = wv & 1;

    const char* Ac = (const char*)hbuf + ((size_t)(rt2 >> 1) * 64) * ACH_B + (rt2 & 1) * 16384;
    const char* Bc = (const char*)W2h + ((size_t)(e * 16 + ct * 2) * 64) * CHUNK_B;

    const f32x4 fz = {0.f, 0.f, 0.f, 0.f};
    f32x4 acc[4][4];
#pragma unroll
    for (int m = 0; m < 4; m++)
#pragma unroll
        for (int n = 0; n < 4; n++) acc[m][n] = fz;

    f16x8 af[4], bf[4];
    int kb_base = (lane >> 4) * 16;

#define ST2_A(kt_, b_) {                                                            \
        const char* s_ = Ac + (size_t)(kt_) * ACH_B + wv * 4096 + lane * 16;        \
        char* d_ = lds + (b_) * 32768 + wv * 4096;                                  \
        gll16(s_, d_); gll16(s_ + 1024, d_ + 1024);                                 \
        gll16(s_ + 2048, d_ + 2048); gll16(s_ + 3072, d_ + 3072); }
#define ST2_B(kt_, b_) {                                                            \
        gll16(Bc + (kt_) * 8192 + wv * 2048 + lane * 16,                             \
              lds + (b_) * 32768 + 16384 + wv * 2048);                               \
        gll16(Bc + (kt_) * 8192 + wv * 2048 + 1024 + lane * 16,                      \
              lds + (b_) * 32768 + 16384 + wv * 2048 + 1024);                        \
        gll16(Bc + 524288 + (kt_) * 8192 + wv * 2048 + lane * 16,                    \
              lds + (b_) * 32768 + 24576 + wv * 2048);                               \
        gll16(Bc + 524288 + (kt_) * 8192 + wv * 2048 + 1024 + lane * 16,             \
              lds + (b_) * 32768 + 24576 + wv * 2048 + 1024); }
#define DS2_A(b_, ks_) _Pragma("unroll") for (int m = 0; m < 4; m++) {              \
        int r_ = wr * 64 + m * 16 + (lane & 15);                                    \
        af[m] = *(const f16x8*)(lds + (b_) * 32768 + r_ * 128 +                     \
                                 (((ks_) * 64 + kb_base) ^ ((r_ & 7) << 4))); }
#define DS2_B(b_, ks_) _Pragma("unroll") for (int n = 0; n < 4; n++) {              \
        int c_ = wc * 64 + n * 16 + (lane & 15);                                    \
        bf[n] = *(const f16x8*)(lds + (b_) * 32768 + 16384 + c_ * 128 +             \
                                 (((ks_) * 64 + kb_base) ^ ((c_ & 7) << 4))); }
#define MM2() _Pragma("unroll") for (int n = 0; n < 4; n++)                         \
        _Pragma("unroll") for (int m = 0; m < 4; m++)                               \
            acc[m][n] = MFMA16(af[m], bf[n], acc[m][n]);

    ST2_A(0, 0); ST2_B(0, 0);
    VMCNT(0);
    RAW_BAR();

    for (int t = 0; t < 64; ++t) {
        int cb = t & 1;
        // ph-a: ks0 | stage A(t+1)
        DS2_A(cb, 0); DS2_B(cb, 0);
        if (t < 63) ST2_A(t + 1, cb ^ 1);
        RAW_BAR();
        __builtin_amdgcn_s_setprio(1); MM2(); __builtin_amdgcn_s_setprio(0);
        RAW_BAR();
        // ph-b: ks1 | stage B(t+1)
        DS2_A(cb, 1); DS2_B(cb, 1);
        if (t < 63) ST2_B(t + 1, cb ^ 1);
        RAW_BAR();
        __builtin_amdgcn_s_setprio(1); MM2(); __builtin_amdgcn_s_setprio(0);
        if (t < 63) { VMCNT(0); }   // next tile fully landed before its ph-a
        RAW_BAR();
    }
#undef ST2_A
#undef ST2_B
#undef DS2_A
#undef DS2_B
#undef MM2

    // epilogue: out[tok] += w * y (exactly 2 commutative adds per element)
#pragma unroll
    for (int m = 0; m < 4; m++) {
#pragma unroll
        for (int i = 0; i < 4; i++) {
            int rr = rt2 * 128 + wr * 64 + m * 16 + (lane >> 4) * 4 + i;
            int tok = row_tok[rr];
            if (tok >= 0) {
                float w = row_w[rr];
                float* orow = out + (size_t)tok * DM + ct * 128 + wc * 64 + (lane & 15);
#pragma unroll
                for (int n = 0; n < 4; n++) atomicAdd(&orow[n * 16], w * acc[m][n][i]);
            }
        }
    }
}

extern "C" void kernel_launch(void* const* d_in, const int* in_sizes, int n_in,
                              void* d_out, int out_size, void* d_ws, size_t ws_size,
                              hipStream_t stream) {
    (void)in_sizes; (void)n_in; (void)out_size; (void)ws_size;
    const float* x  = (const float*)d_in[0];
    const float* Wr = (const float*)d_in[1];
    const float* W1 = (const float*)d_in[2];
    const float* W2 = (const float*)d_in[3];
    const float* W3 = (const float*)d_in[4];
    float* out = (float*)d_out;
    char* ws = (char*)d_ws;

    int* misc  = (int*)ws;           // cnt[8] fill[8] poff[8] texp[40] texp2[80]
    int* cnt   = misc;
    int* fill  = misc + 8;
    int* poff  = misc + 16;
    int* texp  = misc + 24;
    int* texp2 = misc + 64;
    int*    topi    = (int*)(ws + 1024);
    float*  topw    = (float*)(ws + 33792);
    float*  probs   = (float*)(ws + 66560);
    int*    row_tok = (int*)(ws + 197632);       // RCAP ints
    float*  row_w   = (float*)(ws + 238592);     // RCAP floats
    ushort* hbuf    = (ushort*)(ws + 279552);    // 40*64*32768 = 83.9 MB
    ushort* W1h     = (ushort*)(ws + 84165632);  // 64 MB
    ushort* W3h     = (ushort*)(ws + 151274496); // 64 MB
    ushort* xg      = (ushort*)(ws + 218383360); // 21 MB (dead after k_g1)
    ushort* W2h     = (ushort*)(ws + 218383360); // 64 MB, aliases xg -> ends 285492224

    k_init<<<(T_TOK * DM + 1 + 255) / 256, 256, 0, stream>>>(out, misc, row_tok);
    k_router<<<T_TOK, 64, 0, stream>>>(x, Wr, probs, topi, topw, cnt);
    k_scan<<<1, 256, 0, stream>>>(probs, cnt, poff, texp, texp2, out + (size_t)T_TOK * DM);
    k_assign<<<(T_TOK + 255) / 256, 256, 0, stream>>>(topi, topw, poff, fill, row_tok, row_w);

    k_convert<<<dim3(16, 512), 256, 0, stream>>>(W1, W1h, DM);
    k_convert<<<dim3(16, 512), 256, 0, stream>>>(W3, W3h, DM);
    k_gather_t<<<dim3(16, MAXT), 512, 0, stream>>>(x, row_tok, xg);
    k_g1<<<32 * MAXT, 512, 0, stream>>>(xg, W1h, W3h, texp, hbuf);
    k_convert<<<dim3(64, 128), 256, 0, stream>>>(W2, W2h, DF);   // xg dead now
    k_g2<<<8 * MAXT2, 256, 0, stream>>>(hbuf, W2h, texp2, row_tok, row_w, out);
}

// Round 7
// 637.054 us; speedup vs baseline: 1.2108x; 1.0085x over previous
//
#include <hip/hip_runtime.h>

#define T_TOK 4096
#define DM 1024
#define DF 4096
#define NE 8
#define BM 256
#define RCAP 10240      // 8192 + 8*256 worst-case padding
#define MAXT 40         // RCAP / BM (256-row tiles)
#define ACH_B 32768     // [256][64] fp16 swizzled A-chunk
#define CHUNK_B 8192    // [64][64] fp16 swizzled weight chunk

typedef _Float16 f16x8 __attribute__((ext_vector_type(8)));
typedef float f32x4 __attribute__((ext_vector_type(4)));

#define MFMA16(a, b, c) __builtin_amdgcn_mfma_f32_16x16x32_f16(a, b, c, 0, 0, 0)
#define RAW_BAR() __builtin_amdgcn_s_barrier()
#define VMCNT(n) asm volatile("s_waitcnt vmcnt(" #n ")" ::: "memory")

__device__ __forceinline__ ushort f2h_bits(float f) {
    _Float16 h = (_Float16)f;
    return __builtin_bit_cast(unsigned short, h);
}

__device__ __forceinline__ unsigned int pk2(float a, float b) {
    return __builtin_bit_cast(unsigned int, __builtin_amdgcn_cvt_pkrtz(a, b));
}

__device__ __forceinline__ uint4 pack8(float4 a, float4 b) {
    uint4 r;
    r.x = pk2(a.x, a.y); r.y = pk2(a.z, a.w);
    r.z = pk2(b.x, b.y); r.w = pk2(b.z, b.w);
    return r;
}

// async global->LDS, 16B per lane; lds ptr wave-uniform
__device__ __forceinline__ void gll16(const void* g, void* l) {
    __builtin_amdgcn_global_load_lds(
        (const __attribute__((address_space(1))) unsigned int*)g,
        (__attribute__((address_space(3))) unsigned int*)l, 16, 0, 0);
}

// ---------------- init ----------------
__global__ __launch_bounds__(256) void k_init(float* __restrict__ out,
                                              int* __restrict__ misc,
                                              int* __restrict__ row_tok) {
    int i = blockIdx.x * 256 + threadIdx.x;
    if (i < T_TOK * DM + 1) out[i] = 0.f;
    if (i < RCAP) row_tok[i] = -1;
    if (i < 256) misc[i] = 0;   // cnt8 fill8 poff8 texp40
}

// ---------------- router ----------------
__global__ __launch_bounds__(64) void k_router(const float* __restrict__ x,
                                               const float* __restrict__ Wr,
                                               float* __restrict__ probs,
                                               int* __restrict__ topi,
                                               float* __restrict__ topw,
                                               int* __restrict__ cnt) {
    int t = blockIdx.x;
    int lane = threadIdx.x;
    const float* xr = x + (size_t)t * DM;
    float s[NE];
#pragma unroll
    for (int e = 0; e < NE; e++) s[e] = 0.f;
    for (int j = lane; j < DM; j += 64) {
        float xv = xr[j];
#pragma unroll
        for (int e = 0; e < NE; e++) s[e] += xv * Wr[e * DM + j];
    }
#pragma unroll
    for (int off = 32; off > 0; off >>= 1) {
#pragma unroll
        for (int e = 0; e < NE; e++) s[e] += __shfl_xor(s[e], off, 64);
    }
    if (lane == 0) {
        float mx = s[0];
#pragma unroll
        for (int e = 1; e < NE; e++) mx = fmaxf(mx, s[e]);
        float ex[NE], sum = 0.f;
#pragma unroll
        for (int e = 0; e < NE; e++) { ex[e] = expf(s[e] - mx); sum += ex[e]; }
        float inv = 1.f / sum;
        float p[NE];
#pragma unroll
        for (int e = 0; e < NE; e++) { p[e] = ex[e] * inv; probs[t * NE + e] = p[e]; }
        int i0 = 0;
#pragma unroll
        for (int e = 1; e < NE; e++) if (p[e] > p[i0]) i0 = e;
        int i1 = (i0 == 0) ? 1 : 0;
#pragma unroll
        for (int e = 0; e < NE; e++) if (e != i0 && p[e] > p[i1]) i1 = e;
        float w0 = p[i0], w1 = p[i1], winv = 1.f / (w0 + w1);
        topi[2 * t] = i0;     topw[2 * t] = w0 * winv;
        topi[2 * t + 1] = i1; topw[2 * t + 1] = w1 * winv;
        atomicAdd(&cnt[i0], 1);
        atomicAdd(&cnt[i1], 1);
    }
}

// ---------------- scan ----------------
__global__ __launch_bounds__(256) void k_scan(const float* __restrict__ probs,
                                              const int* __restrict__ cnt,
                                              int* __restrict__ poff,
                                              int* __restrict__ texp,
                                              float* __restrict__ aux_out) {
    __shared__ float red[256 * NE];
    int tid = threadIdx.x;
    float part[NE];
#pragma unroll
    for (int e = 0; e < NE; e++) part[e] = 0.f;
    for (int t = tid; t < T_TOK; t += 256) {
#pragma unroll
        for (int e = 0; e < NE; e++) part[e] += probs[t * NE + e];
    }
#pragma unroll
    for (int e = 0; e < NE; e++) red[tid * NE + e] = part[e];
    __syncthreads();
    for (int s2 = 128; s2 > 0; s2 >>= 1) {
        if (tid < s2) {
#pragma unroll
            for (int e = 0; e < NE; e++) red[tid * NE + e] += red[(tid + s2) * NE + e];
        }
        __syncthreads();
    }
    if (tid == 0) {
        float al = 0.f;
#pragma unroll
        for (int e = 0; e < NE; e++) al += red[e] * (float)cnt[e];
        *aux_out = al * (8.0f / (16777216.0f + 1e-6f));
        int run = 0, tix = 0;
        for (int e = 0; e < NE; e++) {
            poff[e] = run;
            int nt = (cnt[e] + BM - 1) / BM;
            for (int i = 0; i < nt; i++) texp[tix++] = e;
            run += nt * BM;
        }
    }
}

// ---------------- assign ----------------
__global__ __launch_bounds__(256) void k_assign(const int* __restrict__ topi,
                                                const float* __restrict__ topw,
                                                const int* __restrict__ poff,
                                                int* __restrict__ fill,
                                                int* __restrict__ row_tok,
                                                float* __restrict__ row_w) {
    int t = blockIdx.x * 256 + threadIdx.x;
    if (t >= T_TOK) return;
#pragma unroll
    for (int k = 0; k < 2; k++) {
        int e = topi[2 * t + k];
        int pos = atomicAdd(&fill[e], 1);
        int r = poff[e] + pos;
        row_tok[r] = t;
        row_w[r] = topw[2 * t + k];
    }
}

// convert fp32 [rows][row_len] -> tile-ordered swizzled fp16 64x64 chunks
__global__ __launch_bounds__(256) void k_convert(const float* __restrict__ src,
                                                 ushort* __restrict__ dst,
                                                 int row_len) {
    int nk = row_len >> 6;
    int kt = blockIdx.x, rt = blockIdx.y;
    int tid = threadIdx.x;
    int r = tid >> 2, c0 = (tid & 3) * 16;
    const float* s = src + (size_t)(rt * 64 + r) * row_len + kt * 64 + c0;
    float4 v0 = *(const float4*)(s);
    float4 v1 = *(const float4*)(s + 4);
    float4 v2 = *(const float4*)(s + 8);
    float4 v3 = *(const float4*)(s + 12);
    char* chunk = (char*)dst + ((size_t)rt * nk + kt) * CHUNK_B;
    int sw = (r & 7) << 4;
    *(uint4*)(chunk + r * 128 + ((2 * c0) ^ sw)) = pack8(v0, v1);
    *(uint4*)(chunk + r * 128 + ((2 * c0 + 16) ^ sw)) = pack8(v2, v3);
}

// gather x rows into [256][64] swizzled fp16 chunks (rt, kt)
__global__ __launch_bounds__(512) void k_gather_t(const float* __restrict__ x,
                                                  const int* __restrict__ row_tok,
                                                  ushort* __restrict__ xg) {
    int kt = blockIdx.x, rt = blockIdx.y;
    int tid = threadIdx.x;
    int r = tid >> 1, c0 = (tid & 1) * 32;
    int tok = row_tok[rt * BM + r];
    char* chunk = (char*)xg + ((size_t)rt * 16 + kt) * ACH_B;
    int sw = (r & 7) << 4;
    if (tok >= 0) {
        const float* s = x + (size_t)tok * DM + kt * 64 + c0;
#pragma unroll
        for (int j = 0; j < 4; j++) {
            float4 va = *(const float4*)(s + j * 8);
            float4 vb = *(const float4*)(s + j * 8 + 4);
            *(uint4*)(chunk + r * 128 + ((c0 * 2 + j * 16) ^ sw)) = pack8(va, vb);
        }
    } else {
        uint4 z = {0, 0, 0, 0};
#pragma unroll
        for (int j = 0; j < 4; j++)
            *(uint4*)(chunk + r * 128 + ((c0 * 2 + j * 16) ^ sw)) = z;
    }
}

// ============ GEMM1: 256 rows x 128 f-cols, dual-B, 8-phase ring-2 ============
__global__ __launch_bounds__(512, 2) void k_g1(const ushort* __restrict__ xg,
                                               const ushort* __restrict__ W1h,
                                               const ushort* __restrict__ W3h,
                                               const int* __restrict__ texp,
                                               ushort* __restrict__ hbuf) {
    __shared__ __align__(16) char lds[131072];  // buf b: A at b*65536, B1 +32768, B3 +49152
    int b = blockIdx.x;
    int sz = (b & 7) * 160 + (b >> 3);          // bijective (1280 = 8*160)
    int ct = sz / MAXT, rt = sz % MAXT;         // ct in [0,32)
    int e = texp[rt];
    int tid = threadIdx.x, lane = tid & 63, wv = tid >> 6;
    int wr = wv >> 1, wc = wv & 1;

    const char* Ac  = (const char*)xg + (size_t)rt * 16 * ACH_B;
    const char* B1c = (const char*)W1h + ((size_t)(e * 64 + ct * 2) * 16) * CHUNK_B;
    const char* B3c = (const char*)W3h + ((size_t)(e * 64 + ct * 2) * 16) * CHUNK_B;

    const f32x4 fz = {0.f, 0.f, 0.f, 0.f};
    f32x4 acc1[4][4], acc3[4][4];
#pragma unroll
    for (int m = 0; m < 4; m++)
#pragma unroll
        for (int n = 0; n < 4; n++) { acc1[m][n] = fz; acc3[m][n] = fz; }

    f16x8 af[4], bf[4];
    int kb_base = (lane >> 4) * 16;

#define ST_A(kt_, b_, h_) {                                                        \
        const char* s_ = Ac + (kt_) * ACH_B + (h_) * 16384 + wv * 2048 + lane * 16; \
        char* d_ = lds + (b_) * 65536 + (h_) * 16384 + wv * 2048;                   \
        gll16(s_, d_); gll16(s_ + 1024, d_ + 1024); }
#define ST_B(Bc_, kt_, b_, off_) {                                                          \
        gll16(Bc_ + (kt_) * 8192 + wv * 1024 + lane * 16,                                    \
              lds + (b_) * 65536 + (off_) + wv * 1024);                                      \
        gll16(Bc_ + 131072 + (kt_) * 8192 + wv * 1024 + lane * 16,                           \
              lds + (b_) * 65536 + (off_) + 8192 + wv * 1024); }
#define DS_A(b_, ks_) _Pragma("unroll") for (int m = 0; m < 4; m++) {              \
        int r_ = wr * 64 + m * 16 + (lane & 15);                                   \
        af[m] = *(const f16x8*)(lds + (b_) * 65536 + r_ * 128 +                    \
                                 (((ks_) * 64 + kb_base) ^ ((r_ & 7) << 4))); }
#define DS_B(b_, off_, ks_) _Pragma("unroll") for (int n = 0; n < 4; n++) {        \
        int c_ = wc * 64 + n * 16 + (lane & 15);                                   \
        bf[n] = *(const f16x8*)(lds + (b_) * 65536 + (off_) + c_ * 128 +           \
                                 (((ks_) * 64 + kb_base) ^ ((c_ & 7) << 4))); }
#define MM(accX) _Pragma("unroll") for (int n = 0; n < 4; n++)                     \
        _Pragma("unroll") for (int m = 0; m < 4; m++)                              \
            accX[m][n] = MFMA16(af[m], bf[n], accX[m][n]);

    ST_A(0, 0, 0); ST_A(0, 0, 1); ST_B(B1c, 0, 0, 32768); ST_B(B3c, 0, 0, 49152);
    VMCNT(2);
    RAW_BAR();

    for (int it = 0; it < 8; ++it) {
        int t1 = 2 * it + 1;
        int t2 = 2 * it + 2;
        DS_A(0, 0); DS_B(0, 32768, 0);
        ST_A(t1, 1, 0);
        RAW_BAR();
        __builtin_amdgcn_s_setprio(1); MM(acc1); __builtin_amdgcn_s_setprio(0);
        VMCNT(2);
        RAW_BAR();
        DS_B(0, 49152, 0);
        ST_A(t1, 1, 1);
        RAW_BAR();
        __builtin_amdgcn_s_setprio(1); MM(acc3); __builtin_amdgcn_s_setprio(0);
        RAW_BAR();
        DS_A(0, 1); DS_B(0, 32768, 1);
        ST_B(B1c, t1, 1, 32768);
        RAW_BAR();
        __builtin_amdgcn_s_setprio(1); MM(acc1); __builtin_amdgcn_s_setprio(0);
        RAW_BAR();
        DS_B(0, 49152, 1);
        ST_B(B3c, t1, 1, 49152);
        RAW_BAR();
        __builtin_amdgcn_s_setprio(1); MM(acc3); __builtin_amdgcn_s_setprio(0);
        VMCNT(2);
        RAW_BAR();
        DS_A(1, 0); DS_B(1, 32768, 0);
        if (it < 7) ST_A(t2, 0, 0);
        RAW_BAR();
        __builtin_amdgcn_s_setprio(1); MM(acc1); __builtin_amdgcn_s_setprio(0);
        if (it < 7) { VMCNT(2); } else { VMCNT(0); }
        RAW_BAR();
        DS_B(1, 49152, 0);
        if (it < 7) ST_A(t2, 0, 1);
        RAW_BAR();
        __builtin_amdgcn_s_setprio(1); MM(acc3); __builtin_amdgcn_s_setprio(0);
        RAW_BAR();
        DS_A(1, 1); DS_B(1, 32768, 1);
        if (it < 7) ST_B(B1c, t2, 0, 32768);
        RAW_BAR();
        __builtin_amdgcn_s_setprio(1); MM(acc1); __builtin_amdgcn_s_setprio(0);
        RAW_BAR();
        DS_B(1, 49152, 1);
        if (it < 7) ST_B(B3c, t2, 0, 49152);
        RAW_BAR();
        __builtin_amdgcn_s_setprio(1); MM(acc3); __builtin_amdgcn_s_setprio(0);
        if (it < 7) { VMCNT(2); }
        RAW_BAR();
    }
#undef ST_A
#undef ST_B
#undef DS_A
#undef DS_B
#undef MM

    // epilogue: silu(a1)*a3 -> hbuf chunks (rt, ct*2 + fl/64), swizzled fp16
#pragma unroll
    for (int m = 0; m < 4; m++) {
#pragma unroll
        for (int i = 0; i < 4; i++) {
            int rl = wr * 64 + m * 16 + (lane >> 4) * 4 + i;   // 0..255
            int sw = (rl & 7) << 4;
#pragma unroll
            for (int n = 0; n < 4; n++) {
                int fl = wc * 64 + n * 16 + (lane & 15);        // 0..127
                float a1 = acc1[m][n][i], a3 = acc3[m][n][i];
                float h = (a1 / (1.f + expf(-a1))) * a3;
                char* hc = (char*)hbuf + ((size_t)rt * 64 + ct * 2 + (fl >> 6)) * ACH_B;
                *(ushort*)(hc + rl * 128 + ((2 * (fl & 63)) ^ sw)) = f2h_bits(h);
            }
        }
    }
}

// ============ GEMM2: 256x128, 8 waves, ring-3 never-drain pipeline ============
__global__ __launch_bounds__(512, 1) void k_g2(const ushort* __restrict__ hbuf,
                                               const ushort* __restrict__ W2h,
                                               const int* __restrict__ texp,
                                               const int* __restrict__ row_tok,
                                               const float* __restrict__ row_w,
                                               float* __restrict__ out) {
    __shared__ __align__(16) char lds[147456];  // 3 bufs x (A 32KB + B 16KB)
    int b = blockIdx.x;
    int sz = (b & 7) * MAXT + (b >> 3);         // bijective (320 = 8*40)
    int ct = sz / MAXT, rt = sz % MAXT;         // ct in [0,8)
    int e = texp[rt];
    int tid = threadIdx.x, lane = tid & 63, wv = tid >> 6;
    int wr = wv >> 1, wc = wv & 1;

    const char* Ac = (const char*)hbuf + (size_t)rt * 64 * ACH_B;   // [kt][256][64]
    const char* Bc = (const char*)W2h + ((size_t)(e * 16 + ct * 2) * 64) * CHUNK_B;

    const f32x4 fz = {0.f, 0.f, 0.f, 0.f};
    f32x4 acc[4][4];
#pragma unroll
    for (int m = 0; m < 4; m++)
#pragma unroll
        for (int n = 0; n < 4; n++) acc[m][n] = fz;

    f16x8 af[4], bf[4];
    int kb_base = (lane >> 4) * 16;

#define BUF3(t_) (((t_) % 3) * 49152)
#define ST2_A(kt_) {                                                                 \
        const char* s_ = Ac + (size_t)(kt_) * ACH_B + wv * 4096 + lane * 16;         \
        char* d_ = lds + BUF3(kt_) + wv * 4096;                                      \
        gll16(s_, d_); gll16(s_ + 1024, d_ + 1024);                                  \
        gll16(s_ + 2048, d_ + 2048); gll16(s_ + 3072, d_ + 3072); }
#define ST2_B(kt_) {                                                                 \
        gll16(Bc + (size_t)(kt_) * 8192 + wv * 1024 + lane * 16,                     \
              lds + BUF3(kt_) + 32768 + wv * 1024);                                  \
        gll16(Bc + 524288 + (size_t)(kt_) * 8192 + wv * 1024 + lane * 16,            \
              lds + BUF3(kt_) + 40960 + wv * 1024); }
#define DS2_A(bo_, ks_) _Pragma("unroll") for (int m = 0; m < 4; m++) {              \
        int r_ = wr * 64 + m * 16 + (lane & 15);                                     \
        af[m] = *(const f16x8*)(lds + (bo_) + r_ * 128 +                             \
                                 (((ks_) * 64 + kb_base) ^ ((r_ & 7) << 4))); }
#define DS2_B(bo_, ks_) _Pragma("unroll") for (int n = 0; n < 4; n++) {              \
        int c_ = wc * 64 + n * 16 + (lane & 15);                                     \
        bf[n] = *(const f16x8*)(lds + (bo_) + 32768 + c_ * 128 +                     \
                                 (((ks_) * 64 + kb_base) ^ ((c_ & 7) << 4))); }
#define MM2() _Pragma("unroll") for (int n = 0; n < 4; n++)                          \
        _Pragma("unroll") for (int m = 0; m < 4; m++)                                \
            acc[m][n] = MFMA16(af[m], bf[n], acc[m][n]);

    // prologue: tiles 0 and 1 in flight; wait tile 0 (oldest 6)
    ST2_A(0); ST2_B(0);
    ST2_A(1); ST2_B(1);
    VMCNT(6);
    RAW_BAR();

    for (int t = 0; t < 64; ++t) {
        int bo = BUF3(t);
        // phA: ks0 | stage A(t+2)
        DS2_A(bo, 0); DS2_B(bo, 0);
        if (t < 62) ST2_A(t + 2);
        RAW_BAR();
        __builtin_amdgcn_s_setprio(1); MM2(); __builtin_amdgcn_s_setprio(0);
        RAW_BAR();
        // phB: ks1 | stage B(t+2)
        DS2_A(bo, 1); DS2_B(bo, 1);
        if (t < 62) ST2_B(t + 2);
        RAW_BAR();
        __builtin_amdgcn_s_setprio(1); MM2(); __builtin_amdgcn_s_setprio(0);
        if (t < 62) { VMCNT(6); }          // retire tile t+1's 6; t+2's stay in flight
        else if (t == 62) { VMCNT(0); }    // last tile must land
        RAW_BAR();
    }
#undef BUF3
#undef ST2_A
#undef ST2_B
#undef DS2_A
#undef DS2_B
#undef MM2

    // epilogue: out[tok] += w * y (exactly 2 commutative adds per element)
#pragma unroll
    for (int m = 0; m < 4; m++) {
#pragma unroll
        for (int i = 0; i < 4; i++) {
            int rr = rt * BM + wr * 64 + m * 16 + (lane >> 4) * 4 + i;
            int tok = row_tok[rr];
            if (tok >= 0) {
                float w = row_w[rr];
                float* orow = out + (size_t)tok * DM + ct * 128 + wc * 64 + (lane & 15);
#pragma unroll
                for (int n = 0; n < 4; n++) atomicAdd(&orow[n * 16], w * acc[m][n][i]);
            }
        }
    }
}

extern "C" void kernel_launch(void* const* d_in, const int* in_sizes, int n_in,
                              void* d_out, int out_size, void* d_ws, size_t ws_size,
                              hipStream_t stream) {
    (void)in_sizes; (void)n_in; (void)out_size; (void)ws_size;
    const float* x  = (const float*)d_in[0];
    const float* Wr = (const float*)d_in[1];
    const float* W1 = (const float*)d_in[2];
    const float* W2 = (const float*)d_in[3];
    const float* W3 = (const float*)d_in[4];
    float* out = (float*)d_out;
    char* ws = (char*)d_ws;

    int* misc  = (int*)ws;           // cnt[8] fill[8] poff[8] texp[40]
    int* cnt   = misc;
    int* fill  = misc + 8;
    int* poff  = misc + 16;
    int* texp  = misc + 24;
    int*    topi    = (int*)(ws + 1024);
    float*  topw    = (float*)(ws + 33792);
    float*  probs   = (float*)(ws + 66560);
    int*    row_tok = (int*)(ws + 197632);       // RCAP ints
    float*  row_w   = (float*)(ws + 238592);     // RCAP floats
    ushort* hbuf    = (ushort*)(ws + 279552);    // 40*64*32768 = 83.9 MB
    ushort* W1h     = (ushort*)(ws + 84165632);  // 64 MB
    ushort* W3h     = (ushort*)(ws + 151274496); // 64 MB
    ushort* xg      = (ushort*)(ws + 218383360); // 21 MB (dead after k_g1)
    ushort* W2h     = (ushort*)(ws + 218383360); // 64 MB, aliases xg -> ends 285492224

    k_init<<<(T_TOK * DM + 1 + 255) / 256, 256, 0, stream>>>(out, misc, row_tok);
    k_router<<<T_TOK, 64, 0, stream>>>(x, Wr, probs, topi, topw, cnt);
    k_scan<<<1, 256, 0, stream>>>(probs, cnt, poff, texp, out + (size_t)T_TOK * DM);
    k_assign<<<(T_TOK + 255) / 256, 256, 0, stream>>>(topi, topw, poff, fill, row_tok, row_w);

    k_convert<<<dim3(16, 512), 256, 0, stream>>>(W1, W1h, DM);
    k_convert<<<dim3(16, 512), 256, 0, stream>>>(W3, W3h, DM);
    k_gather_t<<<dim3(16, MAXT), 512, 0, stream>>>(x, row_tok, xg);
    k_g1<<<32 * MAXT, 512, 0, stream>>>(xg, W1h, W3h, texp, hbuf);
    k_convert<<<dim3(64, 128), 256, 0, stream>>>(W2, W2h, DF);   // xg dead now
    k_g2<<<8 * MAXT, 512, 0, stream>>>(hbuf, W2h, texp, row_tok, row_w, out);
}